// Round 2
// baseline (198.528 us; speedup 1.0000x reference)
//
#include <hip/hip_runtime.h>

// Problem constants (fixed by reference: B=64, T=1024, D=256)
constexpr int Bn = 64;
constexpr int Tn = 1024;
constexpr int Dn = 256;

constexpr int TPB  = 256;   // 4 waves
constexpr int NBLK = Tn;    // one timestep per block; 4 blocks/CU, all resident

using short8 = __attribute__((ext_vector_type(8))) short;   // 8 bf16 (4 VGPRs) — MFMA A/B frag
using f32x16 = __attribute__((ext_vector_type(16))) float;  // MFMA 32x32 accumulator

__device__ __forceinline__ float dot4(const float4& a, const float4& b) {
    return a.x * b.x + a.y * b.y + a.z * b.z + a.w * b.w;
}

// fp32 -> bf16 bits, round-to-nearest-even
__device__ __forceinline__ unsigned int bfbits(float x) {
    unsigned int u = __builtin_bit_cast(unsigned int, x);
    return (u + 0x7FFFu + ((u >> 16) & 1u)) >> 16;
}
__device__ __forceinline__ unsigned int pack_bf2(float lo, float hi) {
    return bfbits(lo) | (bfbits(hi) << 16);
}

__global__ __launch_bounds__(TPB, 4)   // cap VGPR at 128 -> 4 blocks/CU (16 waves/CU)
void cmfm_main(const float* __restrict__ fv, const float* __restrict__ fa,
               const int* __restrict__ labels, float* __restrict__ acc,
               float* __restrict__ out)
{
    // Quarter-D bf16 staging: 64 rows x 64 d = 32 uints/row (128 B). 8 KB per array.
    // 16B-slot XOR swizzle (slot ^ (row&7)) keeps ds_write conflicts at free 2-way.
    __shared__ __align__(16) unsigned int Vb[Bn * 32];
    __shared__ __align__(16) unsigned int Ab[Bn * 32];
    __shared__ float rvs[Bn], ras[Bn];
    __shared__ float wred[4][TPB / 64];

    const int tid  = threadIdx.x;
    const int row  = tid >> 2;      // loader row 0..63
    const int q    = tid & 3;       // quarter-thread of the row (owns f4 indices q+4k)
    const int lane = tid & 63;
    const int wave = tid >> 6;

    const int lab = labels[row];
    const float4* __restrict__ fv4 = reinterpret_cast<const float4*>(fv);
    const float4* __restrict__ fa4 = reinterpret_cast<const float4*>(fa);

    const int t = blockIdx.x;
    const size_t base = ((size_t)row * Tn + t) * (Dn / 4);   // float4 units

    // MFMA geometry: 4 waves -> 2x2 quadrants of the 64x64 cross matrix
    const int i0   = (wave >> 1) * 32;
    const int j0   = (wave & 1) * 32;
    const int mrow = lane & 31;
    const int half = lane >> 5;
    const int rsx  = mrow & 7;                        // read swizzle key ((i0+mrow)&7 == mrow&7)
    const unsigned vrb = (unsigned)(i0 + mrow) * 32;  // uint index of V-row base
    const unsigned arb = (unsigned)(j0 + mrow) * 32;

    const int wsx = row & 7;                          // write swizzle key
    const unsigned wrb = (unsigned)row * 32;

    f32x16 C;
    #pragma unroll
    for (int r = 0; r < 16; ++r) C[r] = 0.f;

    float sqv = 0.f, sqa = 0.f, dva = 0.f;
    float rv = 0.f, ra = 0.f;

    // -------- software-pipelined quarters: prefetch qq+1 while packing/MFMA'ing qq --------
    float4 va[2][4], ab4[2][4];   // two register sets, statically indexed (rule #20)

    #pragma unroll
    for (int k = 0; k < 4; ++k) va[0][k] = fv4[base + q + 4 * k];
    #pragma unroll
    for (int k = 0; k < 4; ++k) ab4[0][k] = fa4[base + q + 4 * k];

    #pragma unroll
    for (int qq = 0; qq < 4; ++qq) {
        const int cur = qq & 1;
        const int nxt = cur ^ 1;

        // issue next quarter's loads first — in flight across pack + barriers + MFMA
        if (qq < 3) {
            #pragma unroll
            for (int k = 0; k < 4; ++k) va[nxt][k]  = fv4[base + (qq + 1) * 16 + q + 4 * k];
            #pragma unroll
            for (int k = 0; k < 4; ++k) ab4[nxt][k] = fa4[base + (qq + 1) * 16 + q + 4 * k];
        }

        // consume current quarter: fp32 norm accumulation + unscaled bf16 pack to LDS
        #pragma unroll
        for (int k = 0; k < 4; ++k) {
            const float4 v = va[cur][k];
            const float4 a = ab4[cur][k];
            sqv += dot4(v, v);
            sqa += dot4(a, a);
            dva += dot4(v, a);
            const int d4l  = q + 4 * k;          // 0..15 within this quarter (float4 units)
            const int slot = d4l >> 1;           // 16B slot (8 bf16), 0..7
            const unsigned idx = wrb + (unsigned)(((slot ^ wsx) << 2) + (d4l & 1) * 2);
            uint2 pv, pa;
            pv.x = pack_bf2(v.x, v.y); pv.y = pack_bf2(v.z, v.w);
            pa.x = pack_bf2(a.x, a.y); pa.y = pack_bf2(a.z, a.w);
            *reinterpret_cast<uint2*>(&Vb[idx]) = pv;   // ds_write_b64
            *reinterpret_cast<uint2*>(&Ab[idx]) = pa;
        }

        if (qq == 3) {
            // full-row norms: reduce across the 4 quarter-threads (adjacent lanes)
            sqv += __shfl_xor(sqv, 1); sqv += __shfl_xor(sqv, 2);
            sqa += __shfl_xor(sqa, 1); sqa += __shfl_xor(sqa, 2);
            dva += __shfl_xor(dva, 1); dva += __shfl_xor(dva, 2);
            rv = 1.f / fmaxf(sqrtf(sqv), 1e-8f);
            ra = 1.f / fmaxf(sqrtf(sqa), 1e-8f);
            if (q == 0) { rvs[row] = rv; ras[row] = ra; }
        }
        __syncthreads();

        // 4 MFMA k-steps (K=16 each) on this quarter; unscaled S accumulates across quarters
        #pragma unroll
        for (int s = 0; s < 4; ++s) {
            const int slotl = s * 2 + half;   // lane-half owns k = 8*half..8*half+7 of each K=16
            const short8 av = *reinterpret_cast<const short8*>(&Vb[vrb + ((slotl ^ rsx) << 2)]);
            const short8 bv = *reinterpret_cast<const short8*>(&Ab[arb + ((slotl ^ rsx) << 2)]);
            C = __builtin_amdgcn_mfma_f32_32x32x16_bf16(av, bv, C, 0, 0, 0);
        }
        __syncthreads();   // LDS fully consumed before next quarter overwrites
    }

    // ---- aligned-pair term (exact fp32, one lane per row) + npos indicator ----
    float pos_acc = 0.f, neg_acc = 0.f, npos_i = 0.f;
    if (q == 0) {
        const float cosd = dva * rv * ra;
        if (lab == 0) { pos_acc = 1.f - cosd; npos_i = 1.f; }   // d_bt = 1 - cos
        else          { neg_acc = cosd; }                        // (1 - d_bt) = cos
    }

    // ---- cross term: fold rv_i * ra_j here; drop diagonal via verified C/D layout ----
    // C/D mapping (m74/m101): col = lane&31, row = (reg&3) + 8*(reg>>2) + 4*(lane>>5)
    const float raj = ras[j0 + mrow];
    float od = 0.f;
    #pragma unroll
    for (int r = 0; r < 16; ++r) {
        const int ri = (r & 3) + 8 * (r >> 2) + 4 * half;
        float c = C[r];
        if (i0 == j0 && ri == mrow) c = 0.f;          // i == j diagonal
        od += rvs[i0 + ri] * raj * c;
    }

    // ---- block reduce ----
    #pragma unroll
    for (int off = 1; off < 64; off <<= 1) {
        pos_acc += __shfl_xor(pos_acc, off);
        neg_acc += __shfl_xor(neg_acc, off);
        od      += __shfl_xor(od, off);
        npos_i  += __shfl_xor(npos_i, off);
    }
    if (lane == 0) {
        wred[0][wave] = pos_acc; wred[1][wave] = neg_acc;
        wred[2][wave] = od;      wred[3][wave] = npos_i;
    }
    __syncthreads();

    // ---- 3 atomics + last-block finalize (removes the cmfm_final dispatch) ----
    if (tid == 0) {
        float p = 0.f, n = 0.f, o = 0.f, npf = 0.f;
        #pragma unroll
        for (int w = 0; w < TPB / 64; ++w) {
            p += wred[0][w]; n += wred[1][w]; o += wred[2][w]; npf += wred[3][w];
        }
        atomicAdd(&acc[0],  p);
        atomicAdd(&acc[16], n);
        atomicAdd(&acc[32], o);
        __threadfence();                                   // partials visible before ticket
        int* ctr = reinterpret_cast<int*>(acc) + 48;       // zeroed by the memset
        const int old = atomicAdd(ctr, 1);
        if (old == NBLK - 1) {                             // last block: all adds visible
            __threadfence();
            const float pos_sum   = atomicAdd(&acc[0],  0.f);   // coherent reads
            const float neg_sum   = atomicAdd(&acc[16], 0.f);
            const float cross_sum = atomicAdd(&acc[32], 0.f);
            const int   np        = (int)(npf + 0.5f);
            const float cnt_pos = (float)np * (float)Tn;
            const float cnt_neg = (float)(Bn - np) * (float)Tn + (float)Bn * (float)(Bn - 1);
            float loss = 0.f;
            if (np > 0) loss += 2.0f * pos_sum / cnt_pos;                     // ALPHA
            loss += (2.0f * neg_sum + 1.0f * cross_sum / (float)Tn) / cnt_neg; // BETA, GAMMA
            out[0] = loss;
        }
    }
}

extern "C" void kernel_launch(void* const* d_in, const int* in_sizes, int n_in,
                              void* d_out, int out_size, void* d_ws, size_t ws_size,
                              hipStream_t stream) {
    const float* fv     = (const float*)d_in[0];
    const float* fa     = (const float*)d_in[1];
    const int*   labels = (const int*)d_in[2];
    float* acc = (float*)d_ws;        // [0]=pos [16]=neg [32]=cross [48]=ticket counter
    float* out = (float*)d_out;

    hipMemsetAsync(acc, 0, 64 * sizeof(float), stream);
    cmfm_main<<<NBLK, TPB, 0, stream>>>(fv, fa, labels, acc, out);
}

// Round 3
// 188.795 us; speedup vs baseline: 1.0516x; 1.0516x over previous
//
#include <hip/hip_runtime.h>

// Problem constants (fixed by reference: B=64, T=1024, D=256)
constexpr int Bn = 64;
constexpr int Tn = 1024;
constexpr int Dn = 256;

constexpr int TPB  = 256;   // 4 waves
constexpr int NBLK = Tn;    // one timestep per block; 4 blocks/CU, all resident

using short8 = __attribute__((ext_vector_type(8))) short;   // 8 bf16 (4 VGPRs) — MFMA A/B frag
using f32x16 = __attribute__((ext_vector_type(16))) float;  // MFMA 32x32 accumulator

__device__ __forceinline__ float dot4(const float4& a, const float4& b) {
    return a.x * b.x + a.y * b.y + a.z * b.z + a.w * b.w;
}

// fp32 -> bf16 bits, round-to-nearest-even
__device__ __forceinline__ unsigned int bfbits(float x) {
    unsigned int u = __builtin_bit_cast(unsigned int, x);
    return (u + 0x7FFFu + ((u >> 16) & 1u)) >> 16;
}
__device__ __forceinline__ unsigned int pack_bf2(float lo, float hi) {
    return bfbits(lo) | (bfbits(hi) << 16);
}

// LDS-ordering barrier that does NOT drain vmcnt: __syncthreads() would emit
// s_waitcnt vmcnt(0) (guide §5, m97 barrier-drain) and kill the global prefetch.
// lgkmcnt(0) retires this wave's ds ops; s_barrier makes them visible to all.
// sched_barrier(0) per rule #18 (keep MFMA/ds from being scheduled across).
__device__ __forceinline__ void lds_barrier() {
    asm volatile("s_waitcnt lgkmcnt(0)" ::: "memory");
    __builtin_amdgcn_sched_barrier(0);
    __builtin_amdgcn_s_barrier();
    __builtin_amdgcn_sched_barrier(0);
}

__global__ __launch_bounds__(TPB, 4)   // cap VGPR at 128 -> 4 blocks/CU (16 waves/CU)
void cmfm_main(const float* __restrict__ fv, const float* __restrict__ fa,
               const int* __restrict__ labels, float* __restrict__ acc,
               float* __restrict__ out)
{
    // Half-D bf16 staging: 64 rows x 128 d = 64 uints/row (256 B). 16 KB per array.
    // 16B-slot XOR swizzle (slot ^ (row&15)): ds_write and ds_read both land at
    // free 2-way bank aliasing (round-1 layout; round-2's 128 B rows were 4-way).
    __shared__ __align__(16) unsigned int Vb[Bn * 64];
    __shared__ __align__(16) unsigned int Ab[Bn * 64];
    __shared__ float rvs[Bn], ras[Bn];
    __shared__ float wred[4][TPB / 64];

    const int tid  = threadIdx.x;
    const int row  = tid >> 2;      // loader row 0..63
    const int q    = tid & 3;       // quarter-thread of the row (owns f4 indices q+4k)
    const int lane = tid & 63;
    const int wave = tid >> 6;

    const int lab = labels[row];
    const float4* __restrict__ fv4 = reinterpret_cast<const float4*>(fv);
    const float4* __restrict__ fa4 = reinterpret_cast<const float4*>(fa);

    const int t = blockIdx.x;
    const size_t base = ((size_t)row * Tn + t) * (Dn / 4);   // float4 units

    // MFMA geometry: 4 waves -> 2x2 quadrants of the 64x64 cross matrix
    const int i0   = (wave >> 1) * 32;
    const int j0   = (wave & 1) * 32;
    const int mrow = lane & 31;
    const int half = lane >> 5;
    const int rsx  = mrow & 15;                       // read swizzle key ((i0+mrow)&15 == mrow&15)
    const unsigned vrb = (unsigned)(i0 + mrow) * 64;  // uint index of V-row base
    const unsigned arb = (unsigned)(j0 + mrow) * 64;

    const int wsx = row & 15;                         // write swizzle key
    const unsigned wrb = (unsigned)row * 64;

    f32x16 C;
    #pragma unroll
    for (int r = 0; r < 16; ++r) C[r] = 0.f;

    float sqv = 0.f, sqa = 0.f, dva = 0.f;

    // ---------------- load h0 ----------------
    float4 v0[8], a0[8];
    #pragma unroll
    for (int k = 0; k < 8; ++k) v0[k] = fv4[base + q + 4 * k];
    #pragma unroll
    for (int k = 0; k < 8; ++k) a0[k] = fa4[base + q + 4 * k];

    // ---------------- pack h0: fp32 norms + unscaled bf16 to LDS ----------------
    #pragma unroll
    for (int k = 0; k < 8; ++k) {
        const float4 v = v0[k], a = a0[k];
        sqv += dot4(v, v); sqa += dot4(a, a); dva += dot4(v, a);
        const int d4l  = q + 4 * k;          // 0..31 within half (float4 units)
        const int slot = d4l >> 1;           // 16B slot (8 bf16), 0..15
        const unsigned idx = wrb + (((unsigned)(slot ^ wsx)) << 2) + (unsigned)((d4l & 1) * 2);
        uint2 pv, pa;
        pv.x = pack_bf2(v.x, v.y); pv.y = pack_bf2(v.z, v.w);
        pa.x = pack_bf2(a.x, a.y); pa.y = pack_bf2(a.z, a.w);
        *reinterpret_cast<uint2*>(&Vb[idx]) = pv;   // ds_write_b64
        *reinterpret_cast<uint2*>(&Ab[idx]) = pa;
    }

    // ---------------- prefetch h1: in flight across barrier + MFMA h0 ----------------
    float4 v1[8], a1[8];
    #pragma unroll
    for (int k = 0; k < 8; ++k) v1[k] = fv4[base + 32 + q + 4 * k];
    #pragma unroll
    for (int k = 0; k < 8; ++k) a1[k] = fa4[base + 32 + q + 4 * k];

    lds_barrier();   // packs h0 visible to all waves; vmcnt NOT drained

    // ---------------- MFMA h0 (8 K=16 steps) ----------------
    #pragma unroll
    for (int s = 0; s < 8; ++s) {
        const int slotl = s * 2 + half;      // lane-half owns k = 8*half..8*half+7 of each K=16
        const short8 av = *reinterpret_cast<const short8*>(&Vb[vrb + (((unsigned)(slotl ^ rsx)) << 2)]);
        const short8 bv = *reinterpret_cast<const short8*>(&Ab[arb + (((unsigned)(slotl ^ rsx)) << 2)]);
        C = __builtin_amdgcn_mfma_f32_32x32x16_bf16(av, bv, C, 0, 0, 0);
    }

    lds_barrier();   // all h0 reads retired before h1 overwrites

    // ---------------- pack h1 (compiler inserts vmcnt waits on first use) ----------------
    #pragma unroll
    for (int k = 0; k < 8; ++k) {
        const float4 v = v1[k], a = a1[k];
        sqv += dot4(v, v); sqa += dot4(a, a); dva += dot4(v, a);
        const int d4l  = q + 4 * k;
        const int slot = d4l >> 1;
        const unsigned idx = wrb + (((unsigned)(slot ^ wsx)) << 2) + (unsigned)((d4l & 1) * 2);
        uint2 pv, pa;
        pv.x = pack_bf2(v.x, v.y); pv.y = pack_bf2(v.z, v.w);
        pa.x = pack_bf2(a.x, a.y); pa.y = pack_bf2(a.z, a.w);
        *reinterpret_cast<uint2*>(&Vb[idx]) = pv;
        *reinterpret_cast<uint2*>(&Ab[idx]) = pa;
    }

    // full-row norms: reduce across the 4 quarter-threads (adjacent lanes)
    sqv += __shfl_xor(sqv, 1); sqv += __shfl_xor(sqv, 2);
    sqa += __shfl_xor(sqa, 1); sqa += __shfl_xor(sqa, 2);
    dva += __shfl_xor(dva, 1); dva += __shfl_xor(dva, 2);
    const float rv = 1.f / fmaxf(sqrtf(sqv), 1e-8f);
    const float ra = 1.f / fmaxf(sqrtf(sqa), 1e-8f);
    if (q == 0) { rvs[row] = rv; ras[row] = ra; }

    lds_barrier();   // packs h1 + rvs/ras visible

    // ---------------- MFMA h1 ----------------
    #pragma unroll
    for (int s = 0; s < 8; ++s) {
        const int slotl = s * 2 + half;
        const short8 av = *reinterpret_cast<const short8*>(&Vb[vrb + (((unsigned)(slotl ^ rsx)) << 2)]);
        const short8 bv = *reinterpret_cast<const short8*>(&Ab[arb + (((unsigned)(slotl ^ rsx)) << 2)]);
        C = __builtin_amdgcn_mfma_f32_32x32x16_bf16(av, bv, C, 0, 0, 0);
    }

    // ---- aligned-pair term (exact fp32, one lane per row) + npos indicator ----
    float pos_acc = 0.f, neg_acc = 0.f, npos_i = 0.f;
    if (q == 0) {
        const float cosd = dva * rv * ra;
        if (lab == 0) { pos_acc = 1.f - cosd; npos_i = 1.f; }   // d_bt = 1 - cos
        else          { neg_acc = cosd; }                        // (1 - d_bt) = cos
    }

    // ---- cross term: fold rv_i * ra_j; drop diagonal via verified C/D layout ----
    // C/D mapping (m74/m101): col = lane&31, row = (reg&3) + 8*(reg>>2) + 4*(lane>>5)
    const float raj = ras[j0 + mrow];
    float od = 0.f;
    #pragma unroll
    for (int r = 0; r < 16; ++r) {
        const int ri = (r & 3) + 8 * (r >> 2) + 4 * half;
        float c = C[r];
        if (i0 == j0 && ri == mrow) c = 0.f;          // i == j diagonal
        od += rvs[i0 + ri] * raj * c;
    }

    // ---- block reduce (plain __syncthreads fine here: nothing left in flight) ----
    #pragma unroll
    for (int off = 1; off < 64; off <<= 1) {
        pos_acc += __shfl_xor(pos_acc, off);
        neg_acc += __shfl_xor(neg_acc, off);
        od      += __shfl_xor(od, off);
        npos_i  += __shfl_xor(npos_i, off);
    }
    if (lane == 0) {
        wred[0][wave] = pos_acc; wred[1][wave] = neg_acc;
        wred[2][wave] = od;      wred[3][wave] = npos_i;
    }
    __syncthreads();

    // ---- 3 atomics + last-block finalize (no separate final dispatch) ----
    if (tid == 0) {
        float p = 0.f, n = 0.f, o = 0.f, npf = 0.f;
        #pragma unroll
        for (int w = 0; w < TPB / 64; ++w) {
            p += wred[0][w]; n += wred[1][w]; o += wred[2][w]; npf += wred[3][w];
        }
        atomicAdd(&acc[0],  p);
        atomicAdd(&acc[16], n);
        atomicAdd(&acc[32], o);
        __threadfence();                                   // partials visible before ticket
        int* ctr = reinterpret_cast<int*>(acc) + 48;       // zeroed by the memset
        const int old = atomicAdd(ctr, 1);
        if (old == NBLK - 1) {                             // last block: all adds visible
            __threadfence();
            const float pos_sum   = atomicAdd(&acc[0],  0.f);   // coherent reads
            const float neg_sum   = atomicAdd(&acc[16], 0.f);
            const float cross_sum = atomicAdd(&acc[32], 0.f);
            const int   np        = (int)(npf + 0.5f);
            const float cnt_pos = (float)np * (float)Tn;
            const float cnt_neg = (float)(Bn - np) * (float)Tn + (float)Bn * (float)(Bn - 1);
            float loss = 0.f;
            if (np > 0) loss += 2.0f * pos_sum / cnt_pos;                      // ALPHA
            loss += (2.0f * neg_sum + 1.0f * cross_sum / (float)Tn) / cnt_neg; // BETA, GAMMA
            out[0] = loss;
        }
    }
}

extern "C" void kernel_launch(void* const* d_in, const int* in_sizes, int n_in,
                              void* d_out, int out_size, void* d_ws, size_t ws_size,
                              hipStream_t stream) {
    const float* fv     = (const float*)d_in[0];
    const float* fa     = (const float*)d_in[1];
    const int*   labels = (const int*)d_in[2];
    float* acc = (float*)d_ws;        // [0]=pos [16]=neg [32]=cross [48]=ticket counter
    float* out = (float*)d_out;

    hipMemsetAsync(acc, 0, 64 * sizeof(float), stream);
    cmfm_main<<<NBLK, TPB, 0, stream>>>(fv, fa, labels, acc, out);
}